// Round 2
// baseline (1055.659 us; speedup 1.0000x reference)
//
#include <hip/hip_runtime.h>

typedef __attribute__((ext_vector_type(8))) __bf16 bf16x8;
typedef __attribute__((ext_vector_type(4))) float f32x4;

#define DEV __device__ __forceinline__

DEV unsigned short f2bf(float f) {
  unsigned u = __float_as_uint(f);
  u = (u + 0x7fffu + ((u >> 16) & 1u)) >> 16;   // round-to-nearest-even
  return (unsigned short)u;
}
DEV float bf2f(unsigned short s) { return __uint_as_float(((unsigned)s) << 16); }
DEV float sigm(float x) { return 1.f / (1.f + expf(-x)); }

DEV uint4 pack8(f32x4 a, f32x4 b) {
  uint4 o;
  o.x = (unsigned)f2bf(a[0]) | ((unsigned)f2bf(a[1]) << 16);
  o.y = (unsigned)f2bf(a[2]) | ((unsigned)f2bf(a[3]) << 16);
  o.z = (unsigned)f2bf(b[0]) | ((unsigned)f2bf(b[1]) << 16);
  o.w = (unsigned)f2bf(b[2]) | ((unsigned)f2bf(b[3]) << 16);
  return o;
}

#define GL16(SRC, LDSB)                                                                    \
  __builtin_amdgcn_global_load_lds(                                                       \
      (const __attribute__((address_space(1))) unsigned int*)(SRC),                       \
      (__attribute__((address_space(3))) unsigned int*)(LDSB), 16, 0, 0)

// ---------------------------------------------------------------------------
// GEMM: C[M x N] = A[M x K] * B^T  (B stored [N x K] row-major bf16)
// 128x128 tile, BK=64, 4 waves, mfma 16x16x32 bf16.
// Double-buffered LDS (64 KB): STAGE(t+1) issued BEFORE compute(t); one
// __syncthreads (vmcnt+lgkm drain) per K-tile.  XOR swizzle kb^=(row&7)<<4
// applied as involution: inverse-swizzled GLOBAL source + swizzled ds_read,
// LDS dest linear (gload_lds requirement, rule #21).
// 1-D grid, bijective XCD chunking (m204), M-major within chunk so an XCD's
// chunk shares its B panel (L2-resident).
// MODE: 0 = f32 out, 1 = bf16 out, 2 = fused-alpha (sigmoid dot qw partials).
// ---------------------------------------------------------------------------
template<int MODE, bool BIAS>
__global__ __launch_bounds__(256)
void gemm_bt(const unsigned short* __restrict__ A, const unsigned short* __restrict__ Bm,
             const float* __restrict__ bias, void* __restrict__ Cv,
             const float* __restrict__ vw1, const float* __restrict__ qwf,
             const int* __restrict__ batchp, int MBk, int N, int K)
{
  __shared__ unsigned short sm[32768];          // 64 KB: 2 x (As[128][64] + Bs[128][64])

  // bijective XCD-chunk swizzle
  const int nwg = gridDim.x;
  const int q = nwg >> 3, r = nwg & 7;
  const int xcd = blockIdx.x & 7, pos = blockIdx.x >> 3;
  const int wgid = (xcd < r ? xcd * (q + 1) : r * (q + 1) + (xcd - r) * q) + pos;
  const int mIdx = wgid % MBk;
  const int nIdx = wgid / MBk;
  const long mTile = (long)mIdx << 7;
  const long nTile = (long)nIdx << 7;

  const int tid  = threadIdx.x;
  const int lane = tid & 63;
  const int wv   = tid >> 6;
  const int wr   = (wv >> 1) << 6;              // wave row offset (0/64)
  const int wc   = (wv & 1) << 6;               // wave col offset (0/64)

  const f32x4 z4 = {0.f, 0.f, 0.f, 0.f};
  f32x4 acc[4][4];
  #pragma unroll
  for (int i = 0; i < 4; ++i)
    #pragma unroll
    for (int j = 0; j < 4; ++j) acc[i][j] = z4;

  const int crow = lane >> 3;                   // row within 8-row chunk
  const int ckb  = (lane & 7) << 4;             // linear kbyte of this lane's 16B

  auto stage = [&](int buf, int k0) {
    char* base = (char*)(sm + buf * 16384);
    #pragma unroll
    for (int i = 0; i < 4; ++i) {
      const int c   = (wv << 2) + i;            // chunk 0..15
      const int row = (c << 3) + crow;          // tile row 0..127
      const int kb  = ckb ^ ((row & 7) << 4);   // pre-swizzled source kbyte
      const unsigned short* sA = A + (mTile + row) * K + k0 + (kb >> 1);
      GL16(sA, base + (c << 10));
      int bn = (int)nTile + row; bn = bn < N ? bn : (N - 1);   // clamp OOB cols
      const unsigned short* sB = Bm + (long)bn * K + k0 + (kb >> 1);
      GL16(sB, base + 16384 + (c << 10));
    }
  };

  const int nt = K >> 6;
  stage(0, 0);
  __syncthreads();
  int cur = 0;
  for (int t = 0; t < nt; ++t) {
    if (t + 1 < nt) stage(cur ^ 1, (t + 1) << 6);     // prefetch flies under compute
    const char* As = (const char*)(sm + cur * 16384);
    const char* Bs = As + 16384;
    #pragma unroll
    for (int kk = 0; kk < 64; kk += 32) {
      const int kbl = (kk + ((lane >> 4) << 3)) << 1;   // logical kbyte of fragment
      bf16x8 af[4], bfv[4];
      #pragma unroll
      for (int mi = 0; mi < 4; ++mi) {
        const int rr = wr + (mi << 4) + (lane & 15);
        af[mi] = *(const bf16x8*)(As + (rr << 7) + (kbl ^ ((rr & 7) << 4)));
      }
      #pragma unroll
      for (int ni = 0; ni < 4; ++ni) {
        const int rr = wc + (ni << 4) + (lane & 15);
        bfv[ni] = *(const bf16x8*)(Bs + (rr << 7) + (kbl ^ ((rr & 7) << 4)));
      }
      #pragma unroll
      for (int mi = 0; mi < 4; ++mi)
        #pragma unroll
        for (int ni = 0; ni < 4; ++ni)
          acc[mi][ni] = __builtin_amdgcn_mfma_f32_16x16x32_bf16(af[mi], bfv[ni], acc[mi][ni], 0, 0, 0);
    }
    __syncthreads();                                  // drains vmcnt (prefetch) + lgkm
    cur ^= 1;
  }

  if constexpr (MODE == 2) {
    // fused alpha: partial_n = sum_col sigm(vw1[batch[row]][col]+gemm) * qw[col]
    // written per (nIdx, wave-col-half) slice; k_sg sums the 4 slices + qb.
    const int NnAll = MBk << 7;
    const int slice = (int)(nIdx * 2 + (wc >> 6));
    #pragma unroll
    for (int mi = 0; mi < 4; ++mi) {
      #pragma unroll
      for (int j = 0; j < 4; ++j) {
        const long row = mTile + wr + (mi << 4) + ((lane >> 4) << 2) + j;
        const long vb = (long)batchp[row] << 8;
        float part = 0.f;
        #pragma unroll
        for (int ni = 0; ni < 4; ++ni) {
          const int col = (int)nTile + wc + (ni << 4) + (lane & 15);
          part += sigm(acc[mi][ni][j] + vw1[vb + col]) * qwf[col];
        }
        #pragma unroll
        for (int off = 1; off < 16; off <<= 1) part += __shfl_xor(part, off, 64);
        if ((lane & 15) == 0) ((float*)Cv)[(long)slice * NnAll + row] = part;
      }
    }
  } else {
    // C/D layout col=lane&15, row=(lane>>4)*4+j (m89-verified)
    #pragma unroll
    for (int ni = 0; ni < 4; ++ni) {
      const long col = nTile + wc + (ni << 4) + (lane & 15);
      if (col < N) {
        float bv = 0.f;
        if constexpr (BIAS) bv = bias[col];
        #pragma unroll
        for (int mi = 0; mi < 4; ++mi) {
          const long row = mTile + wr + (mi << 4) + ((lane >> 4) << 2);
          #pragma unroll
          for (int j = 0; j < 4; ++j) {
            const float v = acc[mi][ni][j] + bv;
            if constexpr (MODE == 1) ((unsigned short*)Cv)[(row + j) * N + col] = f2bf(v);
            else                     ((float*)Cv)[(row + j) * N + col] = v;
          }
        }
      }
    }
  }
}

// ---------------------------------------------------------------------------
// Elementwise / graph kernels
// ---------------------------------------------------------------------------
__global__ void k_cvt8(const float* __restrict__ in, unsigned short* __restrict__ out, long n8)
{
  const long i = (long)blockIdx.x * 256 + threadIdx.x;
  if (i >= n8) return;
  const f32x4 a = *(const f32x4*)(in + i * 8);
  const f32x4 b = *(const f32x4*)(in + i * 8 + 4);
  *(uint4*)(out + i * 8) = pack8(a, b);
}

__global__ void k_tr(const float* __restrict__ g, unsigned short* __restrict__ o)
{
  const int mat = blockIdx.x >> 8;
  const int n   = blockIdx.x & 255;
  const int k   = threadIdx.x;
  o[mat * 65536 + n * 256 + k] = f2bf(g[mat * 65536 + k * 256 + n]);
}

__global__ void k_b12(const float* __restrict__ b1, const float* __restrict__ b2,
                      float* __restrict__ o)
{
  o[threadIdx.x] = b1[threadIdx.x] + b2[threadIdx.x];
}

__global__ void k_gather(const int* __restrict__ x, const float* __restrict__ emb,
                         unsigned short* __restrict__ h)
{
  const long i = (long)blockIdx.x * 256 + threadIdx.x;   // one per 8 dims
  const long node = i >> 5;
  const int  d0 = ((int)i & 31) << 3;
  const long row = (long)x[node] - 1;                    // 1-based ids
  const float* p = emb + row * 256 + d0;
  const f32x4 a = *(const f32x4*)p;
  const f32x4 b = *(const f32x4*)(p + 4);
  *(uint4*)(h + node * 256 + d0) = pack8(a, b);
}

// per-graph scatter-add: block g handles its 20 nodes / 40 edges; thread owns dim d
__global__ void k_scatter(const unsigned short* __restrict__ m, const int* __restrict__ ei,
                          unsigned short* __restrict__ agg, int E)
{
  __shared__ float aggs[20 * 256];
  __shared__ int es[40], ed[40];
  const int g = blockIdx.x;
  const int d = threadIdx.x;
  if (d < 40) es[d] = ei[g * 40 + d];
  if (d >= 128 && d < 168) ed[d - 128] = ei[E + g * 40 + (d - 128)];
  #pragma unroll
  for (int i = 0; i < 20; ++i) aggs[i * 256 + d] = 0.f;
  __syncthreads();
  for (int e = 0; e < 40; ++e) {
    const float mv = bf2f(m[(long)es[e] * 256 + d]);
    const int loc = ed[e] - g * 20;
    aggs[loc * 256 + d] += mv;     // thread-private column: no races
  }
  const long base = (long)g * (20 * 256);
  #pragma unroll
  for (int i = 0; i < 20; ++i)
    agg[base + i * 256 + d] = f2bf(aggs[i * 256 + d]);
}

__global__ void k_gru(const unsigned short* __restrict__ gi, const unsigned short* __restrict__ gh,
                      unsigned short* __restrict__ h)
{
  const long i = (long)blockIdx.x * 256 + threadIdx.x;   // one per 8 dims
  const long node = i >> 5;
  const int  d0 = ((int)i & 31) << 3;
  const long gb = node * 768 + d0;
  const uint4 vir = *(const uint4*)(gi + gb);
  const uint4 viz = *(const uint4*)(gi + gb + 256);
  const uint4 vin = *(const uint4*)(gi + gb + 512);
  const uint4 vhr = *(const uint4*)(gh + gb);
  const uint4 vhz = *(const uint4*)(gh + gb + 256);
  const uint4 vhn = *(const uint4*)(gh + gb + 512);
  const long hb = node * 256 + d0;
  const uint4 vh = *(const uint4*)(h + hb);
  uint4 outv;
  unsigned* po = (unsigned*)&outv;
  #pragma unroll
  for (int j = 0; j < 4; ++j) {
    unsigned res = 0;
    #pragma unroll
    for (int t = 0; t < 2; ++t) {
      const int sh = t * 16;
      const float ir  = bf2f((unsigned short)(((const unsigned*)&vir)[j] >> sh));
      const float iz  = bf2f((unsigned short)(((const unsigned*)&viz)[j] >> sh));
      const float inn = bf2f((unsigned short)(((const unsigned*)&vin)[j] >> sh));
      const float hr  = bf2f((unsigned short)(((const unsigned*)&vhr)[j] >> sh));
      const float hz  = bf2f((unsigned short)(((const unsigned*)&vhz)[j] >> sh));
      const float hn  = bf2f((unsigned short)(((const unsigned*)&vhn)[j] >> sh));
      const float hv  = bf2f((unsigned short)(((const unsigned*)&vh )[j] >> sh));
      const float r  = sigm(ir + hr);
      const float zz = sigm(iz + hz);
      const float nn = tanhf(inn + r * hn);
      const float o  = (1.f - zz) * nn + zz * hv;
      res |= ((unsigned)f2bf(o)) << sh;
    }
    po[j] = res;
  }
  *(uint4*)(h + hb) = outv;
}

__global__ void k_lastidx(const int* __restrict__ batch, int* __restrict__ last, int n, int ng)
{
  const int g = blockIdx.x * blockDim.x + threadIdx.x;
  if (g >= ng) return;
  int lo = 0, hi = n;                     // first idx with batch[idx] > g
  while (lo < hi) { const int mid = (lo + hi) >> 1; if (batch[mid] > g) hi = mid; else lo = mid + 1; }
  last[g] = lo - 1;
}

__global__ void k_vn(const unsigned short* __restrict__ h, const int* __restrict__ last,
                     unsigned short* __restrict__ vn, unsigned short* __restrict__ cat)
{
  const long i = (long)blockIdx.x * 256 + threadIdx.x;
  const long g = i >> 5;
  const int  d0 = ((int)i & 31) << 3;
  const uint4 v = *(const uint4*)(h + (long)last[g] * 256 + d0);
  *(uint4*)(vn + g * 256 + d0) = v;
  *(uint4*)(cat + g * 512 + d0) = v;
}

__global__ void k_sg(const float* __restrict__ alph2, const float* __restrict__ qb,
                     const unsigned short* __restrict__ h, unsigned short* __restrict__ cat, int Nn)
{
  __shared__ float al[20];
  const int g = blockIdx.x, d = threadIdx.x;
  if (d < 20) {
    const int n = g * 20 + d;
    al[d] = qb[0] + alph2[n] + alph2[Nn + n] + alph2[2 * Nn + n] + alph2[3 * Nn + n];
  }
  __syncthreads();
  float s = 0.f;
  const unsigned short* hp = h + (long)g * 20 * 256 + d;
  #pragma unroll
  for (int i = 0; i < 20; ++i) s += al[i] * bf2f(hp[i * 256]);
  cat[(long)g * 512 + 256 + d] = f2bf(s);
}

// ---------------------------------------------------------------------------
extern "C" void kernel_launch(void* const* d_in, const int* in_sizes, int n_in,
                              void* d_out, int out_size, void* d_ws, size_t ws_size,
                              hipStream_t stream)
{
  const int*   x     = (const int*)  d_in[0];
  const int*   ei    = (const int*)  d_in[1];
  const int*   batch = (const int*)  d_in[2];
  const float* emb   = (const float*)d_in[3];
  const float* gw    = (const float*)d_in[4];
  const float* wih   = (const float*)d_in[5];
  const float* whh   = (const float*)d_in[6];
  const float* bih   = (const float*)d_in[7];
  const float* bhh   = (const float*)d_in[8];
  const float* W1    = (const float*)d_in[9];
  const float* b1    = (const float*)d_in[10];
  const float* W2    = (const float*)d_in[11];
  const float* b2    = (const float*)d_in[12];
  const float* qw    = (const float*)d_in[13];
  const float* qb    = (const float*)d_in[14];
  const float* W3    = (const float*)d_in[15];
  const float* b3    = (const float*)d_in[16];

  const int Nn = in_sizes[0];           // 81920 nodes
  const int E  = in_sizes[1] / 2;       // 163840 edges
  const int V  = in_sizes[3] / 256;     // 50000 vocab
  const int B  = out_size / V;          // 4096 graphs

  char* w = (char*)d_ws;
  auto take = [&](size_t bytes) { char* r = w; w += (bytes + 1023) & ~(size_t)1023; return r; };
  unsigned short* h_   = (unsigned short*)take((size_t)Nn * 256 * 2);
  unsigned short* m_   = (unsigned short*)take((size_t)Nn * 256 * 2);
  unsigned short* agg_ = (unsigned short*)take((size_t)Nn * 256 * 2);
  unsigned short* gi_  = (unsigned short*)take((size_t)Nn * 768 * 2);
  unsigned short* gh_  = (unsigned short*)take((size_t)Nn * 768 * 2);
  unsigned short* embb = (unsigned short*)take((size_t)V * 256 * 2);
  unsigned short* gtw  = (unsigned short*)take((size_t)2 * 65536 * 2);
  unsigned short* wihb = (unsigned short*)take((size_t)768 * 256 * 2);
  unsigned short* whhb = (unsigned short*)take((size_t)768 * 256 * 2);
  unsigned short* w1b  = (unsigned short*)take((size_t)65536 * 2);
  unsigned short* w2b  = (unsigned short*)take((size_t)65536 * 2);
  unsigned short* w3b  = (unsigned short*)take((size_t)131072 * 2);
  unsigned short* vnb  = (unsigned short*)take((size_t)B * 256 * 2);
  unsigned short* catb = (unsigned short*)take((size_t)B * 512 * 2);
  unsigned short* shb  = (unsigned short*)take((size_t)B * 256 * 2);
  float*          b12  = (float*)take(256 * 4);
  int*            last = (int*)take((size_t)B * 4);
  float*          alph2= (float*)take((size_t)4 * Nn * 4);
  float* vw1 = (float*)gh_;             // B*256*4 = 4.2 MB aliases dead gh

  const int MBn = Nn / 128;             // 640
  const int MBb = B / 128;              // 32
  const int NBv = (V + 127) / 128;      // 391

  // --- prep: bf16 conversions (+ gated_w transpose), fused biases ---
  k_cvt8<<<dim3(((long)V * 256 / 8 + 255) / 256), 256, 0, stream>>>(emb, embb, (long)V * 256 / 8);
  k_tr  <<<dim3(512), 256, 0, stream>>>(gw, gtw);
  k_cvt8<<<dim3(96),  256, 0, stream>>>(wih, wihb, 768 * 256 / 8);
  k_cvt8<<<dim3(96),  256, 0, stream>>>(whh, whhb, 768 * 256 / 8);
  k_cvt8<<<dim3(32),  256, 0, stream>>>(W1, w1b, 65536 / 8);
  k_cvt8<<<dim3(32),  256, 0, stream>>>(W2, w2b, 65536 / 8);
  k_cvt8<<<dim3(64),  256, 0, stream>>>(W3, w3b, 131072 / 8);
  k_b12 <<<dim3(1),   256, 0, stream>>>(b1, b2, b12);
  k_gather<<<dim3(Nn * 32 / 256), 256, 0, stream>>>(x, emb, h_);

  // --- 2x GatedGraphConv + GRUCell ---
  for (int L = 0; L < 2; ++L) {
    gemm_bt<1, false><<<dim3(MBn * 2), 256, 0, stream>>>(h_, gtw + (size_t)L * 65536, nullptr, m_, nullptr, nullptr, nullptr, MBn, 256, 256);
    k_scatter<<<dim3(B), 256, 0, stream>>>(m_, ei, agg_, E);
    gemm_bt<1, true><<<dim3(MBn * 6), 256, 0, stream>>>(agg_, wihb, bih, gi_, nullptr, nullptr, nullptr, MBn, 768, 256);
    gemm_bt<1, true><<<dim3(MBn * 6), 256, 0, stream>>>(h_, whhb, bhh, gh_, nullptr, nullptr, nullptr, MBn, 768, 256);
    k_gru<<<dim3(Nn * 32 / 256), 256, 0, stream>>>(gi_, gh_, h_);
  }

  // --- attention readout ---
  k_lastidx<<<dim3((B + 255) / 256), 256, 0, stream>>>(batch, last, Nn, B);
  k_vn<<<dim3(B * 32 / 256), 256, 0, stream>>>(h_, last, vnb, catb);
  gemm_bt<0, true><<<dim3(MBb * 2), 256, 0, stream>>>(vnb, w1b, b12, vw1, nullptr, nullptr, nullptr, MBb, 256, 256);
  // fused: alph2 slices = partial sigmoid(vw1[batch]+h@W2^T) . qw
  gemm_bt<2, false><<<dim3(MBn * 2), 256, 0, stream>>>(h_, w2b, nullptr, alph2, vw1, qw, batch, MBn, 256, 256);
  k_sg<<<dim3(B), 256, 0, stream>>>(alph2, qb, h_, catb, Nn);
  gemm_bt<1, true><<<dim3(MBb * 2), 256, 0, stream>>>(catb, w3b, b3, shb, nullptr, nullptr, nullptr, MBb, 256, 512);

  // --- scores = s_h @ emb^T -> d_out (f32) ---
  gemm_bt<0, false><<<dim3(MBb * NBv), 256, 0, stream>>>(shb, embb, nullptr, (float*)d_out, nullptr, nullptr, nullptr, MBb, V, 256);

  (void)n_in; (void)ws_size;
}

// Round 3
// 830.653 us; speedup vs baseline: 1.2709x; 1.2709x over previous
//
#include <hip/hip_runtime.h>

typedef __attribute__((ext_vector_type(8))) __bf16 bf16x8;
typedef __attribute__((ext_vector_type(4))) float f32x4;

#define DEV __device__ __forceinline__

DEV unsigned short f2bf(float f) {
  unsigned u = __float_as_uint(f);
  u = (u + 0x7fffu + ((u >> 16) & 1u)) >> 16;   // round-to-nearest-even
  return (unsigned short)u;
}
DEV float bf2f(unsigned short s) { return __uint_as_float(((unsigned)s) << 16); }
DEV float sigm(float x) { return 1.f / (1.f + expf(-x)); }

DEV uint4 pack8(f32x4 a, f32x4 b) {
  uint4 o;
  o.x = (unsigned)f2bf(a[0]) | ((unsigned)f2bf(a[1]) << 16);
  o.y = (unsigned)f2bf(a[2]) | ((unsigned)f2bf(a[3]) << 16);
  o.z = (unsigned)f2bf(b[0]) | ((unsigned)f2bf(b[1]) << 16);
  o.w = (unsigned)f2bf(b[2]) | ((unsigned)f2bf(b[3]) << 16);
  return o;
}

#define GL16(SRC, LDSB)                                                                    \
  __builtin_amdgcn_global_load_lds(                                                       \
      (const __attribute__((address_space(1))) unsigned int*)(SRC),                       \
      (__attribute__((address_space(3))) unsigned int*)(LDSB), 16, 0, 0)

// ---------------------------------------------------------------------------
// GEMM: C[M x N] = A[M x K] * B^T  (B stored [N x K] row-major bf16)
// R0-proven structure: 128x128 tile, BK=64, 4 waves, 32KB LDS, 2 barriers/step.
// XOR swizzle kb^=(row&7)<<4 as involution (pre-swizzled global src, swizzled
// ds_read, linear LDS dest — rule #21).  2-D grid (x = N tiles, y = M tiles).
// MODE: 0 = f32 out, 1 = bf16 out, 2 = fused-alpha partials.
// ---------------------------------------------------------------------------
template<int MODE, bool BIAS>
__global__ __launch_bounds__(256)
void gemm_bt(const unsigned short* __restrict__ A, const unsigned short* __restrict__ Bm,
             const float* __restrict__ bias, void* __restrict__ Cv,
             const float* __restrict__ vw1, const float* __restrict__ qwf,
             const int* __restrict__ batchp, int M, int N, int K)
{
  __shared__ unsigned short sm[16384];          // 32 KB: As[128][64], Bs[128][64]
  unsigned short* As = sm;
  unsigned short* Bs = sm + 8192;

  const int tid  = threadIdx.x;
  const int lane = tid & 63;
  const int wv   = tid >> 6;
  const int wr   = (wv >> 1) << 6;              // wave row offset (0/64)
  const int wc   = (wv & 1) << 6;               // wave col offset (0/64)
  const long mTile = (long)blockIdx.y << 7;
  const long nTile = (long)blockIdx.x << 7;

  const f32x4 z4 = {0.f, 0.f, 0.f, 0.f};
  f32x4 acc[4][4];
  #pragma unroll
  for (int i = 0; i < 4; ++i)
    #pragma unroll
    for (int j = 0; j < 4; ++j) acc[i][j] = z4;

  const int crow = lane >> 3;                   // row within 8-row chunk
  const int ckb  = (lane & 7) << 4;             // linear kbyte of this lane's 16B

  for (int k0 = 0; k0 < K; k0 += 64) {
    #pragma unroll
    for (int i = 0; i < 4; ++i) {
      const int c   = (wv << 2) + i;            // chunk 0..15
      const int row = (c << 3) + crow;          // tile row 0..127
      const int kb  = ckb ^ ((row & 7) << 4);   // pre-swizzled source kbyte
      const unsigned short* sA = A + (mTile + row) * K + k0 + (kb >> 1);
      GL16(sA, (char*)As + (c << 10));
      int bn = (int)nTile + row; bn = bn < N ? bn : (N - 1);   // clamp OOB cols
      const unsigned short* sB = Bm + (long)bn * K + k0 + (kb >> 1);
      GL16(sB, (char*)Bs + (c << 10));
    }
    __syncthreads();
    #pragma unroll
    for (int kk = 0; kk < 64; kk += 32) {
      const int kbl = (kk + ((lane >> 4) << 3)) << 1;   // logical kbyte of fragment
      bf16x8 af[4], bfv[4];
      #pragma unroll
      for (int mi = 0; mi < 4; ++mi) {
        const int rr = wr + (mi << 4) + (lane & 15);
        af[mi] = *(const bf16x8*)((const char*)As + (rr << 7) + (kbl ^ ((rr & 7) << 4)));
      }
      #pragma unroll
      for (int ni = 0; ni < 4; ++ni) {
        const int rr = wc + (ni << 4) + (lane & 15);
        bfv[ni] = *(const bf16x8*)((const char*)Bs + (rr << 7) + (kbl ^ ((rr & 7) << 4)));
      }
      #pragma unroll
      for (int mi = 0; mi < 4; ++mi)
        #pragma unroll
        for (int ni = 0; ni < 4; ++ni)
          acc[mi][ni] = __builtin_amdgcn_mfma_f32_16x16x32_bf16(af[mi], bfv[ni], acc[mi][ni], 0, 0, 0);
    }
    __syncthreads();
  }

  if constexpr (MODE == 2) {
    // fused alpha: partial = sum_col sigm(vw1[batch[row]][col]+gemm) * qw[col]
    // one slice per (nTile, wave-col-half); k_sg sums 4 slices + qb.
    const int slice = (int)blockIdx.x * 2 + (wc >> 6);
    #pragma unroll
    for (int mi = 0; mi < 4; ++mi) {
      #pragma unroll
      for (int j = 0; j < 4; ++j) {
        const long row = mTile + wr + (mi << 4) + ((lane >> 4) << 2) + j;
        const long vb = (long)batchp[row] << 8;
        float part = 0.f;
        #pragma unroll
        for (int ni = 0; ni < 4; ++ni) {
          const int col = (int)nTile + wc + (ni << 4) + (lane & 15);
          part += sigm(acc[mi][ni][j] + vw1[vb + col]) * qwf[col];
        }
        #pragma unroll
        for (int off = 1; off < 16; off <<= 1) part += __shfl_xor(part, off, 64);
        if ((lane & 15) == 0) ((float*)Cv)[(long)slice * M + row] = part;
      }
    }
  } else {
    // C/D layout col=lane&15, row=(lane>>4)*4+j (m89-verified)
    #pragma unroll
    for (int ni = 0; ni < 4; ++ni) {
      const long col = nTile + wc + (ni << 4) + (lane & 15);
      if (col < N) {
        float bv = 0.f;
        if constexpr (BIAS) bv = bias[col];
        #pragma unroll
        for (int mi = 0; mi < 4; ++mi) {
          const long row = mTile + wr + (mi << 4) + ((lane >> 4) << 2);
          #pragma unroll
          for (int j = 0; j < 4; ++j) {
            const float v = acc[mi][ni][j] + bv;
            if constexpr (MODE == 1) ((unsigned short*)Cv)[(row + j) * N + col] = f2bf(v);
            else                     ((float*)Cv)[(row + j) * N + col] = v;
          }
        }
      }
    }
  }
}

// ---------------------------------------------------------------------------
// Fused dual-GEMM + GRUCell:  h' = GRU(agg @ wih^T + bih, h @ whh^T + bhh, h)
// Block = 128 rows x 64 hidden dims -> computes six 128x64 gate chunks
// (ir,iz,in from agg; hr,hz,hn from h), combines in registers, writes h'.
// 8 waves (2 row-halves x 4 dim-slices), acc[4][6], BK=64, 80KB dynamic LDS:
//   [0,16K)   Aagg[128][64]   [16K,32K) Ah[128][64]
//   [32K,80K) B[6][64][64]    (gate g: rows (g%3)*256+D0 .. +63 of wih/whh)
// Same XOR-swizzle involution as gemm_bt. hout != hin (ping-pong, no race).
// ---------------------------------------------------------------------------
__global__ __launch_bounds__(512, 2)
void k_ggru(const unsigned short* __restrict__ agg, const unsigned short* __restrict__ hin,
            const unsigned short* __restrict__ wihb, const unsigned short* __restrict__ whhb,
            const float* __restrict__ bih, const float* __restrict__ bhh,
            unsigned short* __restrict__ hout)
{
  extern __shared__ unsigned short sm[];        // 80 KB dynamic
  const int tid  = threadIdx.x;
  const int lane = tid & 63;
  const int wv   = tid >> 6;                    // 0..7
  const int rh   = wv >> 2;                     // row half (0/1)
  const int cg   = wv & 3;                      // 16-dim slice (0..3)
  const int D0   = blockIdx.x << 6;             // hidden-dim base (0/64/128/192)
  const long mTile = (long)blockIdx.y << 7;

  const f32x4 z4 = {0.f, 0.f, 0.f, 0.f};
  f32x4 acc[4][6];
  #pragma unroll
  for (int i = 0; i < 4; ++i)
    #pragma unroll
    for (int g = 0; g < 6; ++g) acc[i][g] = z4;

  const int crow = lane >> 3;
  const int ckb  = (lane & 7) << 4;

  for (int k0 = 0; k0 < 256; k0 += 64) {
    // stage 80 x 1KB chunks; wave wv owns chunks wv*10 .. wv*10+9
    #pragma unroll
    for (int i = 0; i < 10; ++i) {
      const int c = wv * 10 + i;
      if (c < 32) {                             // A tiles (agg then h)
        const unsigned short* src = (c < 16) ? agg : hin;
        const int row = ((c & 15) << 3) + crow;
        const int kb  = ckb ^ ((row & 7) << 4);
        GL16(src + (mTile + row) * 256 + k0 + (kb >> 1), (char*)sm + (c << 10));
      } else {                                  // B gate chunks
        const int g  = (c - 32) >> 3;           // 0..5
        const int lr = (((c - 32) & 7) << 3) + crow;   // 0..63
        const unsigned short* Ws = (g < 3) ? wihb : whhb;
        const long grow = (long)((g % 3) * 256 + D0 + lr);
        const int kb = ckb ^ ((lr & 7) << 4);
        GL16(Ws + grow * 256 + k0 + (kb >> 1), (char*)sm + (c << 10));
      }
    }
    __syncthreads();
    #pragma unroll
    for (int kk = 0; kk < 64; kk += 32) {
      const int kbl = (kk + ((lane >> 4) << 3)) << 1;
      bf16x8 fa[4], fh[4], fb[6];
      #pragma unroll
      for (int mi = 0; mi < 4; ++mi) {
        const int r = (rh << 6) + (mi << 4) + (lane & 15);
        const int off = (r << 7) + (kbl ^ ((r & 7) << 4));
        fa[mi] = *(const bf16x8*)((const char*)sm + off);
        fh[mi] = *(const bf16x8*)((const char*)sm + 16384 + off);
      }
      const int lr = (cg << 4) + (lane & 15);
      const int boff = (lr << 7) + (kbl ^ ((lr & 7) << 4));
      #pragma unroll
      for (int g = 0; g < 6; ++g)
        fb[g] = *(const bf16x8*)((const char*)sm + 32768 + (g << 13) + boff);
      #pragma unroll
      for (int mi = 0; mi < 4; ++mi) {
        #pragma unroll
        for (int g = 0; g < 3; ++g)
          acc[mi][g] = __builtin_amdgcn_mfma_f32_16x16x32_bf16(fa[mi], fb[g], acc[mi][g], 0, 0, 0);
        #pragma unroll
        for (int g = 3; g < 6; ++g)
          acc[mi][g] = __builtin_amdgcn_mfma_f32_16x16x32_bf16(fh[mi], fb[g], acc[mi][g], 0, 0, 0);
      }
    }
    __syncthreads();
  }

  // GRU combine (per-lane local) + write h'
  const int d = D0 + (cg << 4) + (lane & 15);
  const float bir = bih[d], biz = bih[256 + d], bin_ = bih[512 + d];
  const float bhr = bhh[d], bhz = bhh[256 + d], bhn  = bhh[512 + d];
  #pragma unroll
  for (int mi = 0; mi < 4; ++mi) {
    #pragma unroll
    for (int j = 0; j < 4; ++j) {
      const long row = mTile + (rh << 6) + (mi << 4) + ((lane >> 4) << 2) + j;
      const float hold = bf2f(hin[row * 256 + d]);
      const float r  = sigm(acc[mi][0][j] + bir + acc[mi][3][j] + bhr);
      const float z  = sigm(acc[mi][1][j] + biz + acc[mi][4][j] + bhz);
      const float n  = tanhf(acc[mi][2][j] + bin_ + r * (acc[mi][5][j] + bhn));
      hout[row * 256 + d] = f2bf((1.f - z) * n + z * hold);
    }
  }
}

// ---------------------------------------------------------------------------
// Elementwise / graph kernels
// ---------------------------------------------------------------------------
__global__ void k_cvt8(const float* __restrict__ in, unsigned short* __restrict__ out, long n8)
{
  const long i = (long)blockIdx.x * 256 + threadIdx.x;
  if (i >= n8) return;
  const f32x4 a = *(const f32x4*)(in + i * 8);
  const f32x4 b = *(const f32x4*)(in + i * 8 + 4);
  *(uint4*)(out + i * 8) = pack8(a, b);
}

__global__ void k_tr(const float* __restrict__ g, unsigned short* __restrict__ o)
{
  const int mat = blockIdx.x >> 8;
  const int n   = blockIdx.x & 255;
  const int k   = threadIdx.x;
  o[mat * 65536 + n * 256 + k] = f2bf(g[mat * 65536 + k * 256 + n]);
}

__global__ void k_b12(const float* __restrict__ b1, const float* __restrict__ b2,
                      float* __restrict__ o)
{
  o[threadIdx.x] = b1[threadIdx.x] + b2[threadIdx.x];
}

__global__ void k_gather(const int* __restrict__ x, const float* __restrict__ emb,
                         unsigned short* __restrict__ h)
{
  const long i = (long)blockIdx.x * 256 + threadIdx.x;   // one per 8 dims
  const long node = i >> 5;
  const int  d0 = ((int)i & 31) << 3;
  const long row = (long)x[node] - 1;                    // 1-based ids
  const float* p = emb + row * 256 + d0;
  const f32x4 a = *(const f32x4*)p;
  const f32x4 b = *(const f32x4*)(p + 4);
  *(uint4*)(h + node * 256 + d0) = pack8(a, b);
}

// per-graph scatter-add: block g handles its 20 nodes / 40 edges; thread owns dim d
__global__ void k_scatter(const unsigned short* __restrict__ m, const int* __restrict__ ei,
                          unsigned short* __restrict__ agg, int E)
{
  __shared__ float aggs[20 * 256];
  __shared__ int es[40], ed[40];
  const int g = blockIdx.x;
  const int d = threadIdx.x;
  if (d < 40) es[d] = ei[g * 40 + d];
  if (d >= 128 && d < 168) ed[d - 128] = ei[E + g * 40 + (d - 128)];
  #pragma unroll
  for (int i = 0; i < 20; ++i) aggs[i * 256 + d] = 0.f;
  __syncthreads();
  for (int e = 0; e < 40; ++e) {
    const float mv = bf2f(m[(long)es[e] * 256 + d]);
    const int loc = ed[e] - g * 20;
    aggs[loc * 256 + d] += mv;     // thread-private column: no races
  }
  const long base = (long)g * (20 * 256);
  #pragma unroll
  for (int i = 0; i < 20; ++i)
    agg[base + i * 256 + d] = f2bf(aggs[i * 256 + d]);
}

__global__ void k_lastidx(const int* __restrict__ batch, int* __restrict__ last, int n, int ng)
{
  const int g = blockIdx.x * blockDim.x + threadIdx.x;
  if (g >= ng) return;
  int lo = 0, hi = n;                     // first idx with batch[idx] > g
  while (lo < hi) { const int mid = (lo + hi) >> 1; if (batch[mid] > g) hi = mid; else lo = mid + 1; }
  last[g] = lo - 1;
}

__global__ void k_vn(const unsigned short* __restrict__ h, const int* __restrict__ last,
                     unsigned short* __restrict__ vn, unsigned short* __restrict__ cat)
{
  const long i = (long)blockIdx.x * 256 + threadIdx.x;
  const long g = i >> 5;
  const int  d0 = ((int)i & 31) << 3;
  const uint4 v = *(const uint4*)(h + (long)last[g] * 256 + d0);
  *(uint4*)(vn + g * 256 + d0) = v;
  *(uint4*)(cat + g * 512 + d0) = v;
}

__global__ void k_sg(const float* __restrict__ alph2, const float* __restrict__ qb,
                     const unsigned short* __restrict__ h, unsigned short* __restrict__ cat, int Nn)
{
  __shared__ float al[20];
  const int g = blockIdx.x, d = threadIdx.x;
  if (d < 20) {
    const int n = g * 20 + d;
    al[d] = qb[0] + alph2[n] + alph2[Nn + n] + alph2[2 * Nn + n] + alph2[3 * Nn + n];
  }
  __syncthreads();
  float s = 0.f;
  const unsigned short* hp = h + (long)g * 20 * 256 + d;
  #pragma unroll
  for (int i = 0; i < 20; ++i) s += al[i] * bf2f(hp[i * 256]);
  cat[(long)g * 512 + 256 + d] = f2bf(s);
}

// ---------------------------------------------------------------------------
extern "C" void kernel_launch(void* const* d_in, const int* in_sizes, int n_in,
                              void* d_out, int out_size, void* d_ws, size_t ws_size,
                              hipStream_t stream)
{
  const int*   x     = (const int*)  d_in[0];
  const int*   ei    = (const int*)  d_in[1];
  const int*   batch = (const int*)  d_in[2];
  const float* emb   = (const float*)d_in[3];
  const float* gw    = (const float*)d_in[4];
  const float* wih   = (const float*)d_in[5];
  const float* whh   = (const float*)d_in[6];
  const float* bih   = (const float*)d_in[7];
  const float* bhh   = (const float*)d_in[8];
  const float* W1    = (const float*)d_in[9];
  const float* b1    = (const float*)d_in[10];
  const float* W2    = (const float*)d_in[11];
  const float* b2    = (const float*)d_in[12];
  const float* qw    = (const float*)d_in[13];
  const float* qb    = (const float*)d_in[14];
  const float* W3    = (const float*)d_in[15];
  const float* b3    = (const float*)d_in[16];

  const int Nn = in_sizes[0];           // 81920 nodes
  const int E  = in_sizes[1] / 2;       // 163840 edges
  const int V  = in_sizes[3] / 256;     // 50000 vocab
  const int B  = out_size / V;          // 4096 graphs

  char* w = (char*)d_ws;
  auto take = [&](size_t bytes) { char* r = w; w += (bytes + 1023) & ~(size_t)1023; return r; };
  unsigned short* h_   = (unsigned short*)take((size_t)Nn * 256 * 2);
  unsigned short* m_   = (unsigned short*)take((size_t)Nn * 256 * 2);
  unsigned short* agg_ = (unsigned short*)take((size_t)Nn * 256 * 2);
  unsigned short* embb = (unsigned short*)take((size_t)V * 256 * 2);
  unsigned short* gtw  = (unsigned short*)take((size_t)2 * 65536 * 2);
  unsigned short* wihb = (unsigned short*)take((size_t)768 * 256 * 2);
  unsigned short* whhb = (unsigned short*)take((size_t)768 * 256 * 2);
  unsigned short* w1b  = (unsigned short*)take((size_t)65536 * 2);
  unsigned short* w2b  = (unsigned short*)take((size_t)65536 * 2);
  unsigned short* w3b  = (unsigned short*)take((size_t)131072 * 2);
  unsigned short* vnb  = (unsigned short*)take((size_t)B * 256 * 2);
  unsigned short* catb = (unsigned short*)take((size_t)B * 512 * 2);
  unsigned short* shb  = (unsigned short*)take((size_t)B * 256 * 2);
  float*          b12  = (float*)take(256 * 4);
  int*            last = (int*)take((size_t)B * 4);
  float*          alph2= (float*)take((size_t)4 * Nn * 4);
  float*          vw1  = (float*)take((size_t)B * 256 * 4);

  const int MBn = Nn / 128;             // 640
  const int MBb = B / 128;              // 32
  const int NBv = (V + 127) / 128;      // 391

  // --- prep: bf16 conversions (+ gated_w transpose), fused biases ---
  k_cvt8<<<dim3(((long)V * 256 / 8 + 255) / 256), 256, 0, stream>>>(emb, embb, (long)V * 256 / 8);
  k_tr  <<<dim3(512), 256, 0, stream>>>(gw, gtw);
  k_cvt8<<<dim3(96),  256, 0, stream>>>(wih, wihb, 768 * 256 / 8);
  k_cvt8<<<dim3(96),  256, 0, stream>>>(whh, whhb, 768 * 256 / 8);
  k_cvt8<<<dim3(32),  256, 0, stream>>>(W1, w1b, 65536 / 8);
  k_cvt8<<<dim3(32),  256, 0, stream>>>(W2, w2b, 65536 / 8);
  k_cvt8<<<dim3(64),  256, 0, stream>>>(W3, w3b, 131072 / 8);
  k_b12 <<<dim3(1),   256, 0, stream>>>(b1, b2, b12);
  k_gather<<<dim3(Nn * 32 / 256), 256, 0, stream>>>(x, emb, h_);

  // --- 2x GatedGraphConv + fused GRUCell (h ping-pongs h_ <-> m_) ---
  unsigned short* hc = h_;
  unsigned short* mb = m_;
  for (int L = 0; L < 2; ++L) {
    gemm_bt<1, false><<<dim3(2, MBn), 256, 0, stream>>>(hc, gtw + (size_t)L * 65536, nullptr, mb,
                                                        nullptr, nullptr, nullptr, Nn, 256, 256);
    k_scatter<<<dim3(B), 256, 0, stream>>>(mb, ei, agg_, E);
    k_ggru<<<dim3(4, MBn), 512, 81920, stream>>>(agg_, hc, wihb, whhb, bih, bhh, mb);
    unsigned short* t = hc; hc = mb; mb = t;    // h' now lives in old m buffer
  }
  // after 2 swaps hc == h_ again

  // --- attention readout ---
  k_lastidx<<<dim3((B + 255) / 256), 256, 0, stream>>>(batch, last, Nn, B);
  k_vn<<<dim3(B * 32 / 256), 256, 0, stream>>>(hc, last, vnb, catb);
  gemm_bt<0, true><<<dim3(2, MBb), 256, 0, stream>>>(vnb, w1b, b12, vw1,
                                                     nullptr, nullptr, nullptr, B, 256, 256);
  // fused: alph2 slices = partial sigmoid(vw1[batch]+h@W2^T) . qw
  gemm_bt<2, false><<<dim3(2, MBn), 256, 0, stream>>>(hc, w2b, nullptr, alph2,
                                                      vw1, qw, batch, Nn, 256, 256);
  k_sg<<<dim3(B), 256, 0, stream>>>(alph2, qb, hc, catb, Nn);
  gemm_bt<1, true><<<dim3(2, MBb), 256, 0, stream>>>(catb, w3b, b3, shb,
                                                     nullptr, nullptr, nullptr, B, 256, 512);

  // --- scores = s_h @ emb^T -> d_out (f32) ---
  gemm_bt<0, false><<<dim3(NBv, MBb), 256, 0, stream>>>(shb, embb, nullptr, (float*)d_out,
                                                        nullptr, nullptr, nullptr, B, V, 256);

  (void)n_in; (void)ws_size;
}